// Round 1
// baseline (4576.183 us; speedup 1.0000x reference)
//
#include <hip/hip_runtime.h>
#include <stdint.h>

typedef unsigned int uint;
typedef unsigned short ushort;
typedef __attribute__((ext_vector_type(8))) short short8;
typedef __attribute__((ext_vector_type(4))) float floatx4;

// ---------- helpers ----------
__device__ inline ushort f2b(float f) {           // fp32 -> bf16 RNE
  union { float f; uint u; } c; c.f = f;
  uint u = c.u;
  u = (u + 0x7fffu + ((u >> 16) & 1u)) >> 16;
  return (ushort)u;
}
__device__ inline float blo(uint u) { union { uint i; float f; } c; c.i = u << 16;          return c.f; }
__device__ inline float bhi(uint u) { union { uint i; float f; } c; c.i = u & 0xffff0000u; return c.f; }

// ---------------------------------------------------------------------------
// Kernel 1: QKV projection.  C[m][n] = sum_k x[m][k] * W[n][k]  (GEMM-BT)
// x: [8192,1024] fp32, W: [1024,1024] fp32 (row = out dim), out: bf16 [8192,1024]
// blockIdx.z in {0,1,2} selects Wq/Wk/Wv and the Q/K/V slice of d_ws.
// 64x64 tile, BK=32, 4 waves each owning a 32x32 quadrant (2x2 MFMA 16x16x32).
// ---------------------------------------------------------------------------
__global__ __launch_bounds__(256) void qkv_gemm(
    const float* __restrict__ x, const float* __restrict__ Wq,
    const float* __restrict__ Wk, const float* __restrict__ Wv,
    ushort* __restrict__ qkv)
{
  __shared__ ushort As[64 * 32];
  __shared__ ushort Bs[64 * 32];

  const int z = blockIdx.z;
  const float* W = (z == 0) ? Wq : (z == 1) ? Wk : Wv;
  ushort* outp = qkv + (size_t)z * (8192u * 1024u);

  const int n0 = blockIdx.x * 64;
  const int r0 = blockIdx.y * 64;
  const int tid = threadIdx.x;

  // staging mapping: 64 rows x 32 k, 8 bf16 per thread
  const int srow = tid >> 2;          // 0..63
  const int skk  = (tid & 3) << 3;    // 0,8,16,24

  // MFMA mapping
  const int lane = tid & 63;
  const int wave = tid >> 6;
  const int l16  = lane & 15;
  const int quad = lane >> 4;
  const int mi   = (wave & 1) << 5;   // 0 or 32
  const int ni   = (wave >> 1) << 5;  // 0 or 32

  floatx4 acc[2][2];
#pragma unroll
  for (int a = 0; a < 2; ++a)
#pragma unroll
    for (int b = 0; b < 2; ++b)
#pragma unroll
      for (int r = 0; r < 4; ++r) acc[a][b][r] = 0.f;

  const float* Ag = x + (size_t)(r0 + srow) * 1024 + skk;
  const float* Bg = W + (size_t)(n0 + srow) * 1024 + skk;
  ushort* Asp = &As[srow * 32 + skk];
  ushort* Bsp = &Bs[srow * 32 + skk];

  for (int k0 = 0; k0 < 1024; k0 += 32) {
    __syncthreads();
    float4 a0 = *(const float4*)(Ag + k0);
    float4 a1 = *(const float4*)(Ag + k0 + 4);
    float4 b0 = *(const float4*)(Bg + k0);
    float4 b1 = *(const float4*)(Bg + k0 + 4);
    short8 va, vb;
    va[0] = (short)f2b(a0.x); va[1] = (short)f2b(a0.y);
    va[2] = (short)f2b(a0.z); va[3] = (short)f2b(a0.w);
    va[4] = (short)f2b(a1.x); va[5] = (short)f2b(a1.y);
    va[6] = (short)f2b(a1.z); va[7] = (short)f2b(a1.w);
    vb[0] = (short)f2b(b0.x); vb[1] = (short)f2b(b0.y);
    vb[2] = (short)f2b(b0.z); vb[3] = (short)f2b(b0.w);
    vb[4] = (short)f2b(b1.x); vb[5] = (short)f2b(b1.y);
    vb[6] = (short)f2b(b1.z); vb[7] = (short)f2b(b1.w);
    *(short8*)Asp = va;
    *(short8*)Bsp = vb;
    __syncthreads();

    short8 afr[2], bfr[2];
    afr[0] = *(const short8*)&As[(mi +  0 + l16) * 32 + quad * 8];
    afr[1] = *(const short8*)&As[(mi + 16 + l16) * 32 + quad * 8];
    bfr[0] = *(const short8*)&Bs[(ni +  0 + l16) * 32 + quad * 8];
    bfr[1] = *(const short8*)&Bs[(ni + 16 + l16) * 32 + quad * 8];
#pragma unroll
    for (int tm = 0; tm < 2; ++tm)
#pragma unroll
      for (int tn = 0; tn < 2; ++tn)
        acc[tm][tn] = __builtin_amdgcn_mfma_f32_16x16x32_bf16(
            afr[tm], bfr[tn], acc[tm][tn], 0, 0, 0);
  }

  // epilogue: D row = quad*4 + reg, col = l16  (verified m89/m91 layout)
#pragma unroll
  for (int tm = 0; tm < 2; ++tm)
#pragma unroll
    for (int tn = 0; tn < 2; ++tn) {
      const int mg = r0 + mi + 16 * tm + quad * 4;
      const int ng = n0 + ni + 16 * tn + l16;
#pragma unroll
      for (int r = 0; r < 4; ++r)
        outp[(size_t)(mg + r) * 1024 + ng] = f2b(acc[tm][tn][r]);
    }
}

// ---------------------------------------------------------------------------
// Kernel 2: flash attention, fp32 math, bf16 Q/K/V from ws.
// Block = 256 threads, 16 query rows; thread t owns q-row (t>>4) and cols
// 8*(t&15)+128*j (j=0..7).  K/V tiles (16x1024 bf16 = 32 KB each) in LDS.
// Online softmax in base-2 domain: scale = (1/32)*log2(e) folded into Q.
// ---------------------------------------------------------------------------
__global__ __launch_bounds__(256) void attn(
    const ushort* __restrict__ Q, const ushort* __restrict__ K,
    const ushort* __restrict__ V, float* __restrict__ out)
{
  __shared__ uint4 sm[4096];          // 64 KB: K tile then V tile
  uint4* Ksm = sm;
  uint4* Vsm = sm + 2048;

  const int tid = threadIdx.x;
  const int b  = blockIdx.y;
  const int q0 = blockIdx.x << 4;
  const int r  = tid >> 4;            // q-row 0..15
  const int cl = tid & 15;
  const float qscale = 1.4426950408889634f / 32.0f;  // log2(e)/sqrt(1024)

  const size_t qrow = (size_t)b * 2048 + q0 + r;
  const uint4* Qu = (const uint4*)(Q + qrow * 1024);

  float q[64], o[64];
#pragma unroll
  for (int j = 0; j < 8; ++j) {
    uint4 t = Qu[cl + (j << 4)];
    q[8*j+0] = blo(t.x) * qscale; q[8*j+1] = bhi(t.x) * qscale;
    q[8*j+2] = blo(t.y) * qscale; q[8*j+3] = bhi(t.y) * qscale;
    q[8*j+4] = blo(t.z) * qscale; q[8*j+5] = bhi(t.z) * qscale;
    q[8*j+6] = blo(t.w) * qscale; q[8*j+7] = bhi(t.w) * qscale;
  }
#pragma unroll
  for (int i = 0; i < 64; ++i) o[i] = 0.f;
  float m = -INFINITY, l = 0.f;

  const uint4* Ku = (const uint4*)K;
  const uint4* Vu = (const uint4*)V;

  for (int kt = 0; kt < 128; ++kt) {
    __syncthreads();
    const size_t gbase = ((size_t)b * 2048 + (kt << 4)) << 7;  // uint4 units
#pragma unroll
    for (int jj = 0; jj < 8; ++jj) {
      int pos = tid + (jj << 8);
      Ksm[pos] = Ku[gbase + pos];
      Vsm[pos] = Vu[gbase + pos];
    }
    __syncthreads();

    // scores: partial dot over this lane's 64-d subset, all 16 k-rows
    float s[16];
#pragma unroll
    for (int k = 0; k < 16; ++k) s[k] = 0.f;
#pragma unroll
    for (int j = 0; j < 8; ++j) {
      const int off = cl + (j << 4);
#pragma unroll
      for (int k = 0; k < 16; ++k) {
        uint4 kv = Ksm[(k << 7) + off];
        s[k] += q[8*j+0]*blo(kv.x) + q[8*j+1]*bhi(kv.x)
              + q[8*j+2]*blo(kv.y) + q[8*j+3]*bhi(kv.y)
              + q[8*j+4]*blo(kv.z) + q[8*j+5]*bhi(kv.z)
              + q[8*j+6]*blo(kv.w) + q[8*j+7]*bhi(kv.w);
      }
    }
    // butterfly-reduce each score across the 16 lanes of this q-row
#pragma unroll
    for (int k = 0; k < 16; ++k) {
      float v = s[k];
      v += __shfl_xor(v, 1);
      v += __shfl_xor(v, 2);
      v += __shfl_xor(v, 4);
      v += __shfl_xor(v, 8);
      s[k] = v;
    }

    float tmax = s[0];
#pragma unroll
    for (int k = 1; k < 16; ++k) tmax = fmaxf(tmax, s[k]);
    float mnew = fmaxf(m, tmax);
    float alpha = exp2f(m - mnew);
    float p[16];
    float rs = 0.f;
#pragma unroll
    for (int k = 0; k < 16; ++k) { p[k] = exp2f(s[k] - mnew); rs += p[k]; }
    l = l * alpha + rs;
    m = mnew;
#pragma unroll
    for (int i = 0; i < 64; ++i) o[i] *= alpha;

    // O += P * V over this k-tile
#pragma unroll
    for (int j = 0; j < 8; ++j) {
      const int off = cl + (j << 4);
#pragma unroll
      for (int k = 0; k < 16; ++k) {
        uint4 vv = Vsm[(k << 7) + off];
        const float pk = p[k];
        o[8*j+0] += pk * blo(vv.x); o[8*j+1] += pk * bhi(vv.x);
        o[8*j+2] += pk * blo(vv.y); o[8*j+3] += pk * bhi(vv.y);
        o[8*j+4] += pk * blo(vv.z); o[8*j+5] += pk * bhi(vv.z);
        o[8*j+6] += pk * blo(vv.w); o[8*j+7] += pk * bhi(vv.w);
      }
    }
  }

  const float inv = 1.0f / l;
  float* orow = out + qrow * 1024;
#pragma unroll
  for (int j = 0; j < 8; ++j) {
    float4 w0 = make_float4(o[8*j+0]*inv, o[8*j+1]*inv, o[8*j+2]*inv, o[8*j+3]*inv);
    float4 w1 = make_float4(o[8*j+4]*inv, o[8*j+5]*inv, o[8*j+6]*inv, o[8*j+7]*inv);
    *(float4*)(orow + 8*cl + 128*j)     = w0;
    *(float4*)(orow + 8*cl + 128*j + 4) = w1;
  }
}

// ---------------------------------------------------------------------------
extern "C" void kernel_launch(void* const* d_in, const int* in_sizes, int n_in,
                              void* d_out, int out_size, void* d_ws, size_t ws_size,
                              hipStream_t stream) {
  const float* x  = (const float*)d_in[0];
  const float* Wq = (const float*)d_in[1];
  const float* Wk = (const float*)d_in[2];
  const float* Wv = (const float*)d_in[3];

  // ws layout: Q,K,V bf16 [8192,1024] each = 48 MB total
  ushort* Qws = (ushort*)d_ws;
  ushort* Kws = Qws + (size_t)8192 * 1024;
  ushort* Vws = Kws + (size_t)8192 * 1024;
  float* outp = (float*)d_out;

  qkv_gemm<<<dim3(16, 128, 3), 256, 0, stream>>>(x, Wq, Wk, Wv, Qws);
  attn<<<dim3(128, 4), 256, 0, stream>>>(Qws, Kws, Vws, outp);
}

// Round 2
// 923.642 us; speedup vs baseline: 4.9545x; 4.9545x over previous
//
#include <hip/hip_runtime.h>
#include <stdint.h>

typedef unsigned int uint;
typedef unsigned short ushort;
typedef __attribute__((ext_vector_type(8))) short short8;
typedef __attribute__((ext_vector_type(4))) float floatx4;

// ---------- helpers ----------
__device__ inline ushort f2b(float f) {           // fp32 -> bf16 RNE
  union { float f; uint u; } c; c.f = f;
  uint u = c.u;
  u = (u + 0x7fffu + ((u >> 16) & 1u)) >> 16;
  return (ushort)u;
}

// ---------------------------------------------------------------------------
// Kernel 1: QKV projection.  C[m][n] = sum_k x[m][k] * W[n][k]  (GEMM-BT)
// x: [8192,1024] fp32, W: [1024,1024] fp32, out bf16.
// z=0 -> Q row-major [8192,1024]; z=1 -> K row-major; z=2 -> V TRANSPOSED
// as Vt[1024][8192] (PV MFMA B-fragment wants k=seq contiguous).
// ---------------------------------------------------------------------------
__global__ __launch_bounds__(256) void qkv_gemm(
    const float* __restrict__ x, const float* __restrict__ Wq,
    const float* __restrict__ Wk, const float* __restrict__ Wv,
    ushort* __restrict__ qkv)
{
  __shared__ ushort As[64 * 32];
  __shared__ ushort Bs[64 * 32];

  const int z = blockIdx.z;
  const float* W = (z == 0) ? Wq : (z == 1) ? Wk : Wv;
  ushort* outp = qkv + (size_t)z * (8192u * 1024u);   // for z==2 this is Vt base

  const int n0 = blockIdx.x * 64;
  const int r0 = blockIdx.y * 64;
  const int tid = threadIdx.x;

  const int srow = tid >> 2;          // 0..63
  const int skk  = (tid & 3) << 3;    // 0,8,16,24

  const int lane = tid & 63;
  const int wave = tid >> 6;
  const int l16  = lane & 15;
  const int quad = lane >> 4;
  const int mi   = (wave & 1) << 5;
  const int ni   = (wave >> 1) << 5;

  floatx4 acc[2][2];
#pragma unroll
  for (int a = 0; a < 2; ++a)
#pragma unroll
    for (int b = 0; b < 2; ++b)
#pragma unroll
      for (int r = 0; r < 4; ++r) acc[a][b][r] = 0.f;

  const float* Ag = x + (size_t)(r0 + srow) * 1024 + skk;
  const float* Bg = W + (size_t)(n0 + srow) * 1024 + skk;
  ushort* Asp = &As[srow * 32 + skk];
  ushort* Bsp = &Bs[srow * 32 + skk];

  for (int k0 = 0; k0 < 1024; k0 += 32) {
    __syncthreads();
    float4 a0 = *(const float4*)(Ag + k0);
    float4 a1 = *(const float4*)(Ag + k0 + 4);
    float4 b0 = *(const float4*)(Bg + k0);
    float4 b1 = *(const float4*)(Bg + k0 + 4);
    short8 va, vb;
    va[0] = (short)f2b(a0.x); va[1] = (short)f2b(a0.y);
    va[2] = (short)f2b(a0.z); va[3] = (short)f2b(a0.w);
    va[4] = (short)f2b(a1.x); va[5] = (short)f2b(a1.y);
    va[6] = (short)f2b(a1.z); va[7] = (short)f2b(a1.w);
    vb[0] = (short)f2b(b0.x); vb[1] = (short)f2b(b0.y);
    vb[2] = (short)f2b(b0.z); vb[3] = (short)f2b(b0.w);
    vb[4] = (short)f2b(b1.x); vb[5] = (short)f2b(b1.y);
    vb[6] = (short)f2b(b1.z); vb[7] = (short)f2b(b1.w);
    *(short8*)Asp = va;
    *(short8*)Bsp = vb;
    __syncthreads();

    short8 afr[2], bfr[2];
    afr[0] = *(const short8*)&As[(mi +  0 + l16) * 32 + quad * 8];
    afr[1] = *(const short8*)&As[(mi + 16 + l16) * 32 + quad * 8];
    bfr[0] = *(const short8*)&Bs[(ni +  0 + l16) * 32 + quad * 8];
    bfr[1] = *(const short8*)&Bs[(ni + 16 + l16) * 32 + quad * 8];
#pragma unroll
    for (int tm = 0; tm < 2; ++tm)
#pragma unroll
      for (int tn = 0; tn < 2; ++tn)
        acc[tm][tn] = __builtin_amdgcn_mfma_f32_16x16x32_bf16(
            afr[tm], bfr[tn], acc[tm][tn], 0, 0, 0);
  }

  // C/D layout: row = quad*4 + reg, col = l16  (verified m89/m91)
#pragma unroll
  for (int tm = 0; tm < 2; ++tm)
#pragma unroll
    for (int tn = 0; tn < 2; ++tn) {
      const int mg = r0 + mi + 16 * tm + quad * 4;
      const int ng = n0 + ni + 16 * tn + l16;
      if (z == 2) {
        // transposed: Vt[ng][mg..mg+3] — one 8B store
        uint lo = (uint)f2b(acc[tm][tn][0]) | ((uint)f2b(acc[tm][tn][1]) << 16);
        uint hi = (uint)f2b(acc[tm][tn][2]) | ((uint)f2b(acc[tm][tn][3]) << 16);
        *(uint2*)&outp[(size_t)ng * 8192 + mg] = make_uint2(lo, hi);
      } else {
#pragma unroll
        for (int r = 0; r < 4; ++r)
          outp[(size_t)(mg + r) * 1024 + ng] = f2b(acc[tm][tn][r]);
      }
    }
}

// ---------------------------------------------------------------------------
// Kernel 2: MFMA flash attention.
// Block: 256 thr (4 waves), 16 q-rows. 32 k-tiles of 64 rows, D chunked x256.
// QK^T: wave w owns score cols 16w..16w+16, accumulates full-D in one C-frag.
// softmax: base-2 domain, shfl row-reduce + LDS cross-wave combine.
// PV: wave w owns O cols w*64..w*64+64 of each 256-chunk; V from transposed Vt.
// LDS strides padded to (stride/4) % 32 == 4 -> max 2-way conflicts (free).
// ---------------------------------------------------------------------------
#define QS_LD   1032            // 1024 + 8 bf16
#define KS_LD    264            // 256 + 8
#define VS_LD     72            // 64 + 8
#define PS_LD     72

__global__ __launch_bounds__(256) void attn(
    const ushort* __restrict__ Q, const ushort* __restrict__ K,
    const ushort* __restrict__ Vt, float* __restrict__ out)
{
  __shared__ ushort Qs[16 * QS_LD];        // 33,024 B
  __shared__ ushort KVs[256 * VS_LD];      // 36,864 B (>= 64*KS_LD=16,896 sh)
  __shared__ ushort Ps[16 * PS_LD];        //  2,304 B
  __shared__ float  redmax[4 * 16];
  __shared__ float  redsum[4 * 16];

  const int tid  = threadIdx.x;
  const int b    = blockIdx.y;
  const int q0   = blockIdx.x << 4;
  const int lane = tid & 63;
  const int w    = tid >> 6;
  const int l16  = lane & 15;
  const int quad = lane >> 4;

  // ---- load Q tile (16 x 1024 bf16) into LDS once ----
  {
    const uint4* Qg = (const uint4*)(Q + ((size_t)b * 2048 + q0) * 1024);
#pragma unroll
    for (int jj = 0; jj < 8; ++jj) {
      int idx = tid + (jj << 8);           // 0..2047
      int row = idx >> 7;                  // 0..15
      int c16 = idx & 127;                 // uint4 within row
      *(uint4*)&Qs[row * QS_LD + c16 * 8] = Qg[row * 128 + c16];
    }
  }

  floatx4 o[16];
#pragma unroll
  for (int i = 0; i < 16; ++i)
#pragma unroll
    for (int r = 0; r < 4; ++r) o[i][r] = 0.f;
  float m[4], l[4];
#pragma unroll
  for (int r = 0; r < 4; ++r) { m[r] = -INFINITY; l[r] = 0.f; }

  const float SCALE = 1.4426950408889634f / 32.0f;   // log2(e)/sqrt(1024)

  for (int kt = 0; kt < 32; ++kt) {
    const int n0 = kt << 6;                // k-row base

    // ================= Phase A: S = Q K^T (full D, chunked) =================
    floatx4 s;
#pragma unroll
    for (int r = 0; r < 4; ++r) s[r] = 0.f;

    for (int dc = 0; dc < 4; ++dc) {
      __syncthreads();                     // KVs free to overwrite
      // stage K chunk [64 rows x 256 d]
      const uint4* Kg = (const uint4*)(K + ((size_t)b * 2048 + n0) * 1024 + dc * 256);
#pragma unroll
      for (int jj = 0; jj < 8; ++jj) {
        int idx = tid + (jj << 8);
        int row = idx >> 5;                // 0..63
        int c16 = idx & 31;                // 0..31
        *(uint4*)&KVs[row * KS_LD + c16 * 8] = Kg[row * 128 + c16];
      }
      __syncthreads();
#pragma unroll
      for (int kk = 0; kk < 8; ++kk) {
        short8 a = *(const short8*)&Qs[l16 * QS_LD + dc * 256 + kk * 32 + quad * 8];
        short8 bb = *(const short8*)&KVs[(w * 16 + l16) * KS_LD + kk * 32 + quad * 8];
        s = __builtin_amdgcn_mfma_f32_16x16x32_bf16(a, bb, s, 0, 0, 0);
      }
    }

    // ================= softmax (online, base-2) =================
    float mx[4], p[4], sm[4];
#pragma unroll
    for (int r = 0; r < 4; ++r) { s[r] *= SCALE; mx[r] = s[r]; }
#pragma unroll
    for (int d = 1; d < 16; d <<= 1)
#pragma unroll
      for (int r = 0; r < 4; ++r) mx[r] = fmaxf(mx[r], __shfl_xor(mx[r], d));
    if (l16 == 0) {
#pragma unroll
      for (int r = 0; r < 4; ++r) redmax[w * 16 + quad * 4 + r] = mx[r];
    }
    __syncthreads();
    float mnew[4], alpha[4];
#pragma unroll
    for (int r = 0; r < 4; ++r) {
      int row = quad * 4 + r;
      float mt = fmaxf(fmaxf(redmax[row], redmax[16 + row]),
                       fmaxf(redmax[32 + row], redmax[48 + row]));
      mnew[r] = fmaxf(m[r], mt);
      alpha[r] = exp2f(m[r] - mnew[r]);
      m[r] = mnew[r];
      p[r] = exp2f(s[r] - mnew[r]);
      sm[r] = p[r];
    }
#pragma unroll
    for (int d = 1; d < 16; d <<= 1)
#pragma unroll
      for (int r = 0; r < 4; ++r) sm[r] += __shfl_xor(sm[r], d);
    if (l16 == 0) {
#pragma unroll
      for (int r = 0; r < 4; ++r) redsum[w * 16 + quad * 4 + r] = sm[r];
    }
    // P -> LDS (bf16, A-frag friendly [row][64])
#pragma unroll
    for (int r = 0; r < 4; ++r)
      Ps[(quad * 4 + r) * PS_LD + w * 16 + l16] = f2b(p[r]);
    __syncthreads();
#pragma unroll
    for (int r = 0; r < 4; ++r) {
      int row = quad * 4 + r;
      float rs = redsum[row] + redsum[16 + row] + redsum[32 + row] + redsum[48 + row];
      l[r] = l[r] * alpha[r] + rs;
    }
    // rescale O
#pragma unroll
    for (int i = 0; i < 16; ++i)
#pragma unroll
      for (int r = 0; r < 4; ++r) o[i][r] *= alpha[r];

    // ================= Phase B: O += P V (chunked over D) =================
    for (int dc = 0; dc < 4; ++dc) {
      __syncthreads();
      // stage V chunk from Vt: [256 d-rows x 64 s]
      const uint4* Vg = (const uint4*)(Vt + (size_t)dc * 256 * 8192 + (size_t)b * 2048 + n0);
#pragma unroll
      for (int jj = 0; jj < 8; ++jj) {
        int idx = tid + (jj << 8);
        int dl  = idx >> 3;                // 0..255
        int c16 = idx & 7;                 // 0..7
        *(uint4*)&KVs[dl * VS_LD + c16 * 8] = Vg[(size_t)dl * 1024 + c16];
      }
      __syncthreads();
      short8 pa[2];
      pa[0] = *(const short8*)&Ps[l16 * PS_LD +  0 + quad * 8];
      pa[1] = *(const short8*)&Ps[l16 * PS_LD + 32 + quad * 8];
#pragma unroll
      for (int n2 = 0; n2 < 4; ++n2) {
        const int dl = w * 64 + n2 * 16 + l16;
        short8 b0 = *(const short8*)&KVs[dl * VS_LD +  0 + quad * 8];
        short8 b1 = *(const short8*)&KVs[dl * VS_LD + 32 + quad * 8];
        o[dc * 4 + n2] = __builtin_amdgcn_mfma_f32_16x16x32_bf16(pa[0], b0, o[dc * 4 + n2], 0, 0, 0);
        o[dc * 4 + n2] = __builtin_amdgcn_mfma_f32_16x16x32_bf16(pa[1], b1, o[dc * 4 + n2], 0, 0, 0);
      }
    }
  }

  // ================= epilogue =================
  float inv[4];
#pragma unroll
  for (int r = 0; r < 4; ++r) inv[r] = 1.0f / l[r];
  const size_t obase = ((size_t)b * 2048 + q0) * 1024;
#pragma unroll
  for (int dc = 0; dc < 4; ++dc)
#pragma unroll
    for (int n2 = 0; n2 < 4; ++n2) {
      const int col = dc * 256 + w * 64 + n2 * 16 + l16;
#pragma unroll
      for (int r = 0; r < 4; ++r)
        out[obase + (size_t)(quad * 4 + r) * 1024 + col] = o[dc * 4 + n2][r] * inv[r];
    }
}

// ---------------------------------------------------------------------------
extern "C" void kernel_launch(void* const* d_in, const int* in_sizes, int n_in,
                              void* d_out, int out_size, void* d_ws, size_t ws_size,
                              hipStream_t stream) {
  const float* x  = (const float*)d_in[0];
  const float* Wq = (const float*)d_in[1];
  const float* Wk = (const float*)d_in[2];
  const float* Wv = (const float*)d_in[3];

  // ws: Q bf16 [8192,1024], K bf16 [8192,1024], Vt bf16 [1024,8192] = 48 MB
  ushort* Qws  = (ushort*)d_ws;
  ushort* Kws  = Qws + (size_t)8192 * 1024;
  ushort* Vtws = Kws + (size_t)8192 * 1024;
  float* outp = (float*)d_out;

  qkv_gemm<<<dim3(16, 128, 3), 256, 0, stream>>>(x, Wq, Wk, Wv, Qws);
  attn<<<dim3(128, 4), 256, 0, stream>>>(Qws, Kws, Vtws, outp);
}

// Round 3
// 324.651 us; speedup vs baseline: 14.0957x; 2.8450x over previous
//
#include <hip/hip_runtime.h>
#include <stdint.h>

typedef unsigned int uint;
typedef unsigned short ushort;
typedef __attribute__((ext_vector_type(8))) short short8;
typedef __attribute__((ext_vector_type(4))) float floatx4;

// ---------- helpers ----------
__device__ inline ushort f2b(float f) {           // fp32 -> bf16 RNE
  union { float f; uint u; } c; c.f = f;
  uint u = c.u;
  u = (u + 0x7fffu + ((u >> 16) & 1u)) >> 16;
  return (ushort)u;
}

__device__ inline void gl_lds16(const ushort* g, ushort* l) {
  // async global->LDS, 16B per lane; LDS side = wave-uniform base + lane*16
  __builtin_amdgcn_global_load_lds(
      (const __attribute__((address_space(1))) void*)g,
      (__attribute__((address_space(3))) void*)l, 16, 0, 0);
}

// ---------------------------------------------------------------------------
// fp32 -> bf16 bulk convert, 8 elem/thread
// ---------------------------------------------------------------------------
__global__ __launch_bounds__(256) void cvt(const float* __restrict__ s,
                                           ushort* __restrict__ d, int n8) {
  int i = blockIdx.x * 256 + threadIdx.x;
  if (i >= n8) return;
  float4 a = ((const float4*)s)[i * 2];
  float4 b = ((const float4*)s)[i * 2 + 1];
  short8 v;
  v[0] = (short)f2b(a.x); v[1] = (short)f2b(a.y);
  v[2] = (short)f2b(a.z); v[3] = (short)f2b(a.w);
  v[4] = (short)f2b(b.x); v[5] = (short)f2b(b.y);
  v[6] = (short)f2b(b.z); v[7] = (short)f2b(b.w);
  ((short8*)d)[i] = v;
}

// ---------------------------------------------------------------------------
// m97-style GEMM-BT:  C[m][n] = scale * sum_k A[m][k] * B[n][k]
// 128x128 tile, BK=32, 256 thr (4 waves, 2x2 wave grid, 4x4 16x16x32 MFMA).
// global_load_lds width-16 staging, unpadded [128][32] LDS tiles.
// MODE 0: C bf16 row-major   MODE 1: C bf16 TRANSPOSED (C[n][m], ldc = col stride)
// MODE 2: C fp32 row-major * scale   MODE 3: C fp32 row-major
// ---------------------------------------------------------------------------
template <int MODE>
__global__ __launch_bounds__(256) void gemm_bt(
    const ushort* __restrict__ A, int lda, size_t sA,
    const ushort* __restrict__ B, int ldb, size_t sB,
    void* __restrict__ C, int ldc, size_t sC,
    int K, float scale)
{
  __shared__ ushort As[128 * 32];
  __shared__ ushort Bs[128 * 32];

  const int tid = threadIdx.x;
  const int bz  = blockIdx.z;
  A += (size_t)bz * sA;
  B += (size_t)bz * sB;

  const int m0 = blockIdx.y * 128;
  const int n0 = blockIdx.x * 128;

  const int lane = tid & 63;
  const int w    = tid >> 6;
  const int l16  = lane & 15;
  const int quad = lane >> 4;
  const int mw   = w >> 1;            // 0/1 : m-half
  const int nw   = w & 1;             // 0/1 : n-half

  // staging: chunk c in [0,512): row=c>>2, col8=(c&3)*8 ; thread t -> chunks t, t+256
  const int srow = tid >> 2;
  const int scol = (tid & 3) * 8;
  const ushort* ag0 = A + (size_t)(m0 + srow) * lda + scol;
  const ushort* ag1 = A + (size_t)(m0 + 64 + srow) * lda + scol;
  const ushort* bg0 = B + (size_t)(n0 + srow) * ldb + scol;
  const ushort* bg1 = B + (size_t)(n0 + 64 + srow) * ldb + scol;
  ushort* al0 = &As[w * 512];               // wave-uniform LDS bases
  ushort* al1 = &As[2048 + w * 512];
  ushort* bl0 = &Bs[w * 512];
  ushort* bl1 = &Bs[2048 + w * 512];

  floatx4 acc[4][4];
#pragma unroll
  for (int i = 0; i < 4; ++i)
#pragma unroll
    for (int j = 0; j < 4; ++j)
#pragma unroll
      for (int r = 0; r < 4; ++r) acc[i][j][r] = 0.f;

  for (int k0 = 0; k0 < K; k0 += 32) {
    __syncthreads();
    gl_lds16(ag0, al0);
    gl_lds16(ag1, al1);
    gl_lds16(bg0, bl0);
    gl_lds16(bg1, bl1);
    ag0 += 32; ag1 += 32; bg0 += 32; bg1 += 32;
    __syncthreads();

    short8 af[4], bf[4];
#pragma unroll
    for (int i = 0; i < 4; ++i)
      af[i] = *(const short8*)&As[(mw * 64 + i * 16 + l16) * 32 + quad * 8];
#pragma unroll
    for (int j = 0; j < 4; ++j)
      bf[j] = *(const short8*)&Bs[(nw * 64 + j * 16 + l16) * 32 + quad * 8];
#pragma unroll
    for (int i = 0; i < 4; ++i)
#pragma unroll
      for (int j = 0; j < 4; ++j)
        acc[i][j] = __builtin_amdgcn_mfma_f32_16x16x32_bf16(af[i], bf[j], acc[i][j], 0, 0, 0);
  }

  // epilogue; C/D layout: row = quad*4 + r, col = l16 (verified m89/m91)
#pragma unroll
  for (int i = 0; i < 4; ++i)
#pragma unroll
    for (int j = 0; j < 4; ++j) {
      const int mg = m0 + mw * 64 + i * 16 + quad * 4;
      const int ng = n0 + nw * 64 + j * 16 + l16;
      if (MODE == 0) {
        ushort* Cb = (ushort*)C + (size_t)bz * sC;
#pragma unroll
        for (int r = 0; r < 4; ++r)
          Cb[(size_t)(mg + r) * ldc + ng] = f2b(acc[i][j][r]);
      } else if (MODE == 1) {
        ushort* Cb = (ushort*)C + (size_t)bz * sC;
        uint lo = (uint)f2b(acc[i][j][0]) | ((uint)f2b(acc[i][j][1]) << 16);
        uint hi = (uint)f2b(acc[i][j][2]) | ((uint)f2b(acc[i][j][3]) << 16);
        *(uint2*)&Cb[(size_t)ng * ldc + mg] = make_uint2(lo, hi);
      } else {
        float* Cb = (float*)C + (size_t)bz * sC;
#pragma unroll
        for (int r = 0; r < 4; ++r)
          Cb[(size_t)(mg + r) * ldc + ng] =
              (MODE == 2) ? acc[i][j][r] * scale : acc[i][j][r];
      }
    }
}

// ---------------------------------------------------------------------------
// Row softmax over 2048 fp32 scores (already in base-2 domain), writes the
// NORMALIZED probabilities as bf16 in-place at the start of the fp32 row.
// One block (256 thr) per row; 8 elems/thread.
// ---------------------------------------------------------------------------
__global__ __launch_bounds__(256) void softmax_row(float* __restrict__ S) {
  __shared__ float red[8];
  const int t = threadIdx.x;
  const int w = t >> 6;
  float* row = S + (size_t)blockIdx.x * 2048;

  float4 v0 = *(const float4*)(row + t * 8);
  float4 v1 = *(const float4*)(row + t * 8 + 4);
  float v[8] = {v0.x, v0.y, v0.z, v0.w, v1.x, v1.y, v1.z, v1.w};

  float mx = v[0];
#pragma unroll
  for (int i = 1; i < 8; ++i) mx = fmaxf(mx, v[i]);
#pragma unroll
  for (int d = 1; d < 64; d <<= 1) mx = fmaxf(mx, __shfl_xor(mx, d));
  if ((t & 63) == 0) red[w] = mx;
  __syncthreads();
  mx = fmaxf(fmaxf(red[0], red[1]), fmaxf(red[2], red[3]));

  float p[8], sum = 0.f;
#pragma unroll
  for (int i = 0; i < 8; ++i) { p[i] = exp2f(v[i] - mx); sum += p[i]; }
#pragma unroll
  for (int d = 1; d < 64; d <<= 1) sum += __shfl_xor(sum, d);
  if ((t & 63) == 0) red[4 + w] = sum;
  __syncthreads();
  const float inv = 1.0f / (red[4] + red[5] + red[6] + red[7]);

  short8 o;
#pragma unroll
  for (int i = 0; i < 8; ++i) o[i] = (short)f2b(p[i] * inv);
  *(short8*)((ushort*)row + t * 8) = o;   // safe: all reads done before syncs
}

// ===========================================================================
// ===== legacy fallback (proven, 48 MB ws): R2 qkv_gemm + flash attn ========
// ===========================================================================
__global__ __launch_bounds__(256) void qkv_gemm(
    const float* __restrict__ x, const float* __restrict__ Wq,
    const float* __restrict__ Wk, const float* __restrict__ Wv,
    ushort* __restrict__ qkv)
{
  __shared__ ushort As[64 * 32];
  __shared__ ushort Bs[64 * 32];
  const int z = blockIdx.z;
  const float* W = (z == 0) ? Wq : (z == 1) ? Wk : Wv;
  ushort* outp = qkv + (size_t)z * (8192u * 1024u);
  const int n0 = blockIdx.x * 64;
  const int r0 = blockIdx.y * 64;
  const int tid = threadIdx.x;
  const int srow = tid >> 2;
  const int skk  = (tid & 3) << 3;
  const int lane = tid & 63;
  const int wave = tid >> 6;
  const int l16  = lane & 15;
  const int quad = lane >> 4;
  const int mi   = (wave & 1) << 5;
  const int ni   = (wave >> 1) << 5;
  floatx4 acc[2][2];
#pragma unroll
  for (int a = 0; a < 2; ++a)
#pragma unroll
    for (int b = 0; b < 2; ++b)
#pragma unroll
      for (int r = 0; r < 4; ++r) acc[a][b][r] = 0.f;
  const float* Ag = x + (size_t)(r0 + srow) * 1024 + skk;
  const float* Bg = W + (size_t)(n0 + srow) * 1024 + skk;
  ushort* Asp = &As[srow * 32 + skk];
  ushort* Bsp = &Bs[srow * 32 + skk];
  for (int k0 = 0; k0 < 1024; k0 += 32) {
    __syncthreads();
    float4 a0 = *(const float4*)(Ag + k0);
    float4 a1 = *(const float4*)(Ag + k0 + 4);
    float4 b0 = *(const float4*)(Bg + k0);
    float4 b1 = *(const float4*)(Bg + k0 + 4);
    short8 va, vb;
    va[0] = (short)f2b(a0.x); va[1] = (short)f2b(a0.y);
    va[2] = (short)f2b(a0.z); va[3] = (short)f2b(a0.w);
    va[4] = (short)f2b(a1.x); va[5] = (short)f2b(a1.y);
    va[6] = (short)f2b(a1.z); va[7] = (short)f2b(a1.w);
    vb[0] = (short)f2b(b0.x); vb[1] = (short)f2b(b0.y);
    vb[2] = (short)f2b(b0.z); vb[3] = (short)f2b(b0.w);
    vb[4] = (short)f2b(b1.x); vb[5] = (short)f2b(b1.y);
    vb[6] = (short)f2b(b1.z); vb[7] = (short)f2b(b1.w);
    *(short8*)Asp = va;
    *(short8*)Bsp = vb;
    __syncthreads();
    short8 afr[2], bfr[2];
    afr[0] = *(const short8*)&As[(mi +  0 + l16) * 32 + quad * 8];
    afr[1] = *(const short8*)&As[(mi + 16 + l16) * 32 + quad * 8];
    bfr[0] = *(const short8*)&Bs[(ni +  0 + l16) * 32 + quad * 8];
    bfr[1] = *(const short8*)&Bs[(ni + 16 + l16) * 32 + quad * 8];
#pragma unroll
    for (int tm = 0; tm < 2; ++tm)
#pragma unroll
      for (int tn = 0; tn < 2; ++tn)
        acc[tm][tn] = __builtin_amdgcn_mfma_f32_16x16x32_bf16(
            afr[tm], bfr[tn], acc[tm][tn], 0, 0, 0);
  }
#pragma unroll
  for (int tm = 0; tm < 2; ++tm)
#pragma unroll
    for (int tn = 0; tn < 2; ++tn) {
      const int mg = r0 + mi + 16 * tm + quad * 4;
      const int ng = n0 + ni + 16 * tn + l16;
      if (z == 2) {
        uint lo = (uint)f2b(acc[tm][tn][0]) | ((uint)f2b(acc[tm][tn][1]) << 16);
        uint hi = (uint)f2b(acc[tm][tn][2]) | ((uint)f2b(acc[tm][tn][3]) << 16);
        *(uint2*)&outp[(size_t)ng * 8192 + mg] = make_uint2(lo, hi);
      } else {
#pragma unroll
        for (int r = 0; r < 4; ++r)
          outp[(size_t)(mg + r) * 1024 + ng] = f2b(acc[tm][tn][r]);
      }
    }
}

#define QS_LD   1032
#define KS_LD    264
#define VS_LD     72
#define PS_LD     72

__global__ __launch_bounds__(256) void attn(
    const ushort* __restrict__ Q, const ushort* __restrict__ K,
    const ushort* __restrict__ Vt, float* __restrict__ out)
{
  __shared__ ushort Qs[16 * QS_LD];
  __shared__ ushort KVs[256 * VS_LD];
  __shared__ ushort Ps[16 * PS_LD];
  __shared__ float  redmax[4 * 16];
  __shared__ float  redsum[4 * 16];
  const int tid  = threadIdx.x;
  const int b    = blockIdx.y;
  const int q0   = blockIdx.x << 4;
  const int lane = tid & 63;
  const int w    = tid >> 6;
  const int l16  = lane & 15;
  const int quad = lane >> 4;
  {
    const uint4* Qg = (const uint4*)(Q + ((size_t)b * 2048 + q0) * 1024);
#pragma unroll
    for (int jj = 0; jj < 8; ++jj) {
      int idx = tid + (jj << 8);
      int row = idx >> 7;
      int c16 = idx & 127;
      *(uint4*)&Qs[row * QS_LD + c16 * 8] = Qg[row * 128 + c16];
    }
  }
  floatx4 o[16];
#pragma unroll
  for (int i = 0; i < 16; ++i)
#pragma unroll
    for (int r = 0; r < 4; ++r) o[i][r] = 0.f;
  float m[4], l[4];
#pragma unroll
  for (int r = 0; r < 4; ++r) { m[r] = -INFINITY; l[r] = 0.f; }
  const float SCALE = 1.4426950408889634f / 32.0f;
  for (int kt = 0; kt < 32; ++kt) {
    const int n0 = kt << 6;
    floatx4 s;
#pragma unroll
    for (int r = 0; r < 4; ++r) s[r] = 0.f;
    for (int dc = 0; dc < 4; ++dc) {
      __syncthreads();
      const uint4* Kg = (const uint4*)(K + ((size_t)b * 2048 + n0) * 1024 + dc * 256);
#pragma unroll
      for (int jj = 0; jj < 8; ++jj) {
        int idx = tid + (jj << 8);
        int row = idx >> 5;
        int c16 = idx & 31;
        *(uint4*)&KVs[row * KS_LD + c16 * 8] = Kg[row * 128 + c16];
      }
      __syncthreads();
#pragma unroll
      for (int kk = 0; kk < 8; ++kk) {
        short8 a = *(const short8*)&Qs[l16 * QS_LD + dc * 256 + kk * 32 + quad * 8];
        short8 bb = *(const short8*)&KVs[(w * 16 + l16) * KS_LD + kk * 32 + quad * 8];
        s = __builtin_amdgcn_mfma_f32_16x16x32_bf16(a, bb, s, 0, 0, 0);
      }
    }
    float mx[4], p[4], sm[4];
#pragma unroll
    for (int r = 0; r < 4; ++r) { s[r] *= SCALE; mx[r] = s[r]; }
#pragma unroll
    for (int d = 1; d < 16; d <<= 1)
#pragma unroll
      for (int r = 0; r < 4; ++r) mx[r] = fmaxf(mx[r], __shfl_xor(mx[r], d));
    if (l16 == 0) {
#pragma unroll
      for (int r = 0; r < 4; ++r) redmax[w * 16 + quad * 4 + r] = mx[r];
    }
    __syncthreads();
    float mnew[4], alpha[4];
#pragma unroll
    for (int r = 0; r < 4; ++r) {
      int row = quad * 4 + r;
      float mt = fmaxf(fmaxf(redmax[row], redmax[16 + row]),
                       fmaxf(redmax[32 + row], redmax[48 + row]));
      mnew[r] = fmaxf(m[r], mt);
      alpha[r] = exp2f(m[r] - mnew[r]);
      m[r] = mnew[r];
      p[r] = exp2f(s[r] - mnew[r]);
      sm[r] = p[r];
    }
#pragma unroll
    for (int d = 1; d < 16; d <<= 1)
#pragma unroll
      for (int r = 0; r < 4; ++r) sm[r] += __shfl_xor(sm[r], d);
    if (l16 == 0) {
#pragma unroll
      for (int r = 0; r < 4; ++r) redsum[w * 16 + quad * 4 + r] = sm[r];
    }
#pragma unroll
    for (int r = 0; r < 4; ++r)
      Ps[(quad * 4 + r) * PS_LD + w * 16 + l16] = f2b(p[r]);
    __syncthreads();
#pragma unroll
    for (int r = 0; r < 4; ++r) {
      int row = quad * 4 + r;
      float rs = redsum[row] + redsum[16 + row] + redsum[32 + row] + redsum[48 + row];
      l[r] = l[r] * alpha[r] + rs;
    }
#pragma unroll
    for (int i = 0; i < 16; ++i)
#pragma unroll
      for (int r = 0; r < 4; ++r) o[i][r] *= alpha[r];
    for (int dc = 0; dc < 4; ++dc) {
      __syncthreads();
      const uint4* Vg = (const uint4*)(Vt + (size_t)dc * 256 * 8192 + (size_t)b * 2048 + n0);
#pragma unroll
      for (int jj = 0; jj < 8; ++jj) {
        int idx = tid + (jj << 8);
        int dl  = idx >> 3;
        int c16 = idx & 7;
        *(uint4*)&KVs[dl * VS_LD + c16 * 8] = Vg[(size_t)dl * 1024 + c16];
      }
      __syncthreads();
      short8 pa[2];
      pa[0] = *(const short8*)&Ps[l16 * PS_LD +  0 + quad * 8];
      pa[1] = *(const short8*)&Ps[l16 * PS_LD + 32 + quad * 8];
#pragma unroll
      for (int n2 = 0; n2 < 4; ++n2) {
        const int dl = w * 64 + n2 * 16 + l16;
        short8 b0 = *(const short8*)&KVs[dl * VS_LD +  0 + quad * 8];
        short8 b1 = *(const short8*)&KVs[dl * VS_LD + 32 + quad * 8];
        o[dc * 4 + n2] = __builtin_amdgcn_mfma_f32_16x16x32_bf16(pa[0], b0, o[dc * 4 + n2], 0, 0, 0);
        o[dc * 4 + n2] = __builtin_amdgcn_mfma_f32_16x16x32_bf16(pa[1], b1, o[dc * 4 + n2], 0, 0, 0);
      }
    }
  }
  float inv[4];
#pragma unroll
  for (int r = 0; r < 4; ++r) inv[r] = 1.0f / l[r];
  const size_t obase = ((size_t)b * 2048 + q0) * 1024;
#pragma unroll
  for (int dc = 0; dc < 4; ++dc)
#pragma unroll
    for (int n2 = 0; n2 < 4; ++n2) {
      const int col = dc * 256 + w * 64 + n2 * 16 + l16;
#pragma unroll
      for (int r = 0; r < 4; ++r)
        out[obase + (size_t)(quad * 4 + r) * 1024 + col] = o[dc * 4 + n2][r] * inv[r];
    }
}

// ---------------------------------------------------------------------------
extern "C" void kernel_launch(void* const* d_in, const int* in_sizes, int n_in,
                              void* d_out, int out_size, void* d_ws, size_t ws_size,
                              hipStream_t stream) {
  const float* x  = (const float*)d_in[0];
  const float* Wq = (const float*)d_in[1];
  const float* Wk = (const float*)d_in[2];
  const float* Wv = (const float*)d_in[3];
  float* outp = (float*)d_out;

  const float SCALE = 1.4426950408889634f / 32.0f;   // log2(e)/sqrt(1024)

  const size_t NEED_1B   = 90177536;    // base 70 MiB + one-batch S (16 MiB)
  const size_t NEED_FULL = 140509184;   // base + full S (64 MiB)

  if (ws_size >= NEED_1B) {
    ushort* xb = (ushort*)d_ws;                 // [8192][1024] bf16
    ushort* Wb = xb + (size_t)8192 * 1024;      // 3x [1024][1024] bf16
    ushort* Qb = Wb + (size_t)3 * 1024 * 1024;  // [8192][1024]
    ushort* Kb = Qb + (size_t)8192 * 1024;      // [8192][1024]
    ushort* Vt = Kb + (size_t)8192 * 1024;      // [1024][8192] (d-major)
    float*  S  = (float*)(Vt + (size_t)8192 * 1024);

    cvt<<<4096, 256, 0, stream>>>(x,  xb, 1048576);
    cvt<<<512,  256, 0, stream>>>(Wq, Wb,                       131072);
    cvt<<<512,  256, 0, stream>>>(Wk, Wb + (size_t)1024 * 1024, 131072);
    cvt<<<512,  256, 0, stream>>>(Wv, Wb + (size_t)2048 * 1024, 131072);

    // QKV projections
    gemm_bt<0><<<dim3(8, 64, 1), 256, 0, stream>>>(
        xb, 1024, 0, Wb, 1024, 0, Qb, 1024, 0, 1024, 1.f);
    gemm_bt<0><<<dim3(8, 64, 1), 256, 0, stream>>>(
        xb, 1024, 0, Wb + (size_t)1024 * 1024, 1024, 0, Kb, 1024, 0, 1024, 1.f);
    gemm_bt<1><<<dim3(8, 64, 1), 256, 0, stream>>>(
        xb, 1024, 0, Wb + (size_t)2048 * 1024, 1024, 0, Vt, 8192, 0, 1024, 1.f);

    if (ws_size >= NEED_FULL) {
      gemm_bt<2><<<dim3(16, 16, 4), 256, 0, stream>>>(
          Qb, 1024, (size_t)2048 * 1024, Kb, 1024, (size_t)2048 * 1024,
          S, 2048, (size_t)2048 * 2048, 1024, SCALE);
      softmax_row<<<8192, 256, 0, stream>>>(S);
      gemm_bt<3><<<dim3(8, 16, 4), 256, 0, stream>>>(
          (const ushort*)S, 4096, (size_t)2048 * 4096, Vt, 8192, 2048,
          outp, 1024, (size_t)2048 * 1024, 2048, 1.f);
    } else {
      for (int b = 0; b < 4; ++b) {
        gemm_bt<2><<<dim3(16, 16, 1), 256, 0, stream>>>(
            Qb + (size_t)b * 2048 * 1024, 1024, 0,
            Kb + (size_t)b * 2048 * 1024, 1024, 0,
            S, 2048, 0, 1024, SCALE);
        softmax_row<<<2048, 256, 0, stream>>>(S);
        gemm_bt<3><<<dim3(8, 16, 1), 256, 0, stream>>>(
            (const ushort*)S, 4096, 0, Vt + (size_t)b * 2048, 8192, 0,
            outp + (size_t)b * 2048 * 1024, 1024, 0, 2048, 1.f);
      }
    }
  } else {
    // legacy 48 MB path (proven)
    ushort* Qws  = (ushort*)d_ws;
    ushort* Kws  = Qws + (size_t)8192 * 1024;
    ushort* Vtws = Kws + (size_t)8192 * 1024;
    qkv_gemm<<<dim3(16, 128, 3), 256, 0, stream>>>(x, Wq, Wk, Wv, Qws);
    attn<<<dim3(128, 4), 256, 0, stream>>>(Qws, Kws, Vtws, outp);
  }
}

// Round 4
// 261.487 us; speedup vs baseline: 17.5006x; 1.2416x over previous
//
#include <hip/hip_runtime.h>
#include <stdint.h>

typedef unsigned int uint;
typedef unsigned short ushort;
typedef __attribute__((ext_vector_type(8))) short short8;
typedef __attribute__((ext_vector_type(4))) float floatx4;

// ---------- helpers ----------
__device__ inline ushort f2b(float f) {           // fp32 -> bf16 RNE
  union { float f; uint u; } c; c.f = f;
  uint u = c.u;
  u = (u + 0x7fffu + ((u >> 16) & 1u)) >> 16;
  return (ushort)u;
}

__device__ inline void gl_lds16(const ushort* g, ushort* l) {
  // async global->LDS, 16B/lane; LDS dest = wave-uniform base + lane*16
  __builtin_amdgcn_global_load_lds(
      (const __attribute__((address_space(1))) void*)g,
      (__attribute__((address_space(3))) void*)l, 16, 0, 0);
}

// ---------------------------------------------------------------------------
// One-shot fp32->bf16 convert: x (8M elems) + Wq/Wk/Wv (1M each) -> xb, Wb.
// 8 elems/thread. Grid 5632 blocks x 256.
// ---------------------------------------------------------------------------
__global__ __launch_bounds__(256) void cvt_all(
    const float* __restrict__ x,  const float* __restrict__ wq,
    const float* __restrict__ wk, const float* __restrict__ wv,
    ushort* __restrict__ xb, ushort* __restrict__ wb)
{
  const int b = blockIdx.x;
  const float* s; ushort* d; int i;
  if (b < 4096) {                       // x: 4096 blocks
    s = x; d = xb; i = b * 256 + threadIdx.x;
  } else {                              // W: 3 x 512 blocks
    int t = b - 4096;
    int wsel = t >> 9;
    s = (wsel == 0) ? wq : (wsel == 1) ? wk : wv;
    d = wb + (size_t)wsel * (1024u * 1024u);
    i = (t & 511) * 256 + threadIdx.x;
  }
  float4 a = ((const float4*)s)[i * 2];
  float4 c = ((const float4*)s)[i * 2 + 1];
  short8 v;
  v[0] = (short)f2b(a.x); v[1] = (short)f2b(a.y);
  v[2] = (short)f2b(a.z); v[3] = (short)f2b(a.w);
  v[4] = (short)f2b(c.x); v[5] = (short)f2b(c.y);
  v[6] = (short)f2b(c.z); v[7] = (short)f2b(c.w);
  ((short8*)d)[i] = v;
}

// ---------------------------------------------------------------------------
// GEMM-BT:  C[m][n] = scale * sum_k A[m][k] * B[n][k]
// 128x128 tile, BK=64, 256 thr (2x2 waves, 4x4 MFMA 16x16x32 per wave).
// global_load_lds width-16 staging into XOR-swizzled [128][64] LDS tiles:
//   16B-chunk position p holds global chunk p ^ sw(row), sw(r)=(r^(r>>3))&7
//   -> fragment reads are 2-way bank aliased (free, m136), staging stays
//      lane-contiguous as gl_lds requires (m104/m108).
// MODE 2: C fp32 row-major * scale
// MODE 3: C fp32 row-major
// MODE 4: QKV split epilogue. C = Qb base; n<1024 -> Q row-major,
//         n<2048 -> K row-major, else -> Vt transposed [1024][8192].
// ---------------------------------------------------------------------------
template <int MODE>
__global__ __launch_bounds__(256) void gemm_bt(
    const ushort* __restrict__ A, int lda, size_t sA,
    const ushort* __restrict__ B, int ldb, size_t sB,
    void* __restrict__ C, int ldc, size_t sC,
    int K, float scale)
{
  __shared__ ushort As[128 * 64];
  __shared__ ushort Bs[128 * 64];

  const int tid = threadIdx.x;
  const int bz  = blockIdx.z;
  A += (size_t)bz * sA;
  B += (size_t)bz * sB;

  const int m0 = blockIdx.y * 128;
  const int n0 = blockIdx.x * 128;

  const int lane = tid & 63;
  const int w    = tid >> 6;
  const int l16  = lane & 15;
  const int quad = lane >> 4;
  const int mw   = w >> 1;
  const int nw   = w & 1;

  // ---- staging pointers (4 calls cover 128 rows; 8 lanes per 128B row) ----
  const ushort* agp[4];
  const ushort* bgp[4];
#pragma unroll
  for (int c4 = 0; c4 < 4; ++c4) {
    int r   = c4 * 32 + (tid >> 3);          // tile row 0..127
    int sw  = (r ^ (r >> 3)) & 7;
    int col = ((tid & 7) ^ sw) * 8;          // swizzled 16B chunk in k
    agp[c4] = A + (size_t)(m0 + r) * lda + col;
    bgp[c4] = B + (size_t)(n0 + r) * ldb + col;
  }

  // ---- fragment LDS offsets (loop-invariant); h=1 offset = h=0 ^ 32 ----
  int aoff[4], boff[4];
#pragma unroll
  for (int i = 0; i < 4; ++i) {
    int ra = mw * 64 + i * 16 + l16;
    aoff[i] = ra * 64 + ((quad ^ ((ra ^ (ra >> 3)) & 7)) * 8);
    int rb = nw * 64 + i * 16 + l16;
    boff[i] = rb * 64 + ((quad ^ ((rb ^ (rb >> 3)) & 7)) * 8);
  }

  floatx4 acc[4][4];
#pragma unroll
  for (int i = 0; i < 4; ++i)
#pragma unroll
    for (int j = 0; j < 4; ++j)
#pragma unroll
      for (int r = 0; r < 4; ++r) acc[i][j][r] = 0.f;

  for (int k0 = 0; k0 < K; k0 += 64) {
    __syncthreads();
#pragma unroll
    for (int c4 = 0; c4 < 4; ++c4) {
      gl_lds16(agp[c4], &As[(c4 * 32 + w * 8) * 64]);
      gl_lds16(bgp[c4], &Bs[(c4 * 32 + w * 8) * 64]);
      agp[c4] += 64; bgp[c4] += 64;
    }
    __syncthreads();

#pragma unroll
    for (int h = 0; h < 2; ++h) {
      short8 af[4], bf[4];
#pragma unroll
      for (int i = 0; i < 4; ++i) {
        af[i] = *(const short8*)&As[aoff[i] ^ (h * 32)];
        bf[i] = *(const short8*)&Bs[boff[i] ^ (h * 32)];
      }
#pragma unroll
      for (int i = 0; i < 4; ++i)
#pragma unroll
        for (int j = 0; j < 4; ++j)
          acc[i][j] = __builtin_amdgcn_mfma_f32_16x16x32_bf16(
              af[i], bf[j], acc[i][j], 0, 0, 0);
    }
  }

  // ---- epilogue; C/D: row = quad*4 + r, col = l16 (verified m89/m91) ----
#pragma unroll
  for (int i = 0; i < 4; ++i)
#pragma unroll
    for (int j = 0; j < 4; ++j) {
      const int mg = m0 + mw * 64 + i * 16 + quad * 4;
      const int ng = n0 + nw * 64 + j * 16 + l16;
      if (MODE == 2 || MODE == 3) {
        float* Cb = (float*)C + (size_t)bz * sC;
#pragma unroll
        for (int r = 0; r < 4; ++r)
          Cb[(size_t)(mg + r) * ldc + ng] =
              (MODE == 2) ? acc[i][j][r] * scale : acc[i][j][r];
      } else {  // MODE 4: QKV split
        ushort* Qo = (ushort*)C;
        if (ng < 2048) {
          ushort* dst = Qo + (size_t)(ng >> 10) * (8192u * 1024u);
          const int nn = ng & 1023;
#pragma unroll
          for (int r = 0; r < 4; ++r)
            dst[(size_t)(mg + r) * 1024 + nn] = f2b(acc[i][j][r]);
        } else {
          ushort* Vo = Qo + (size_t)2 * 8192 * 1024;
          uint lo = (uint)f2b(acc[i][j][0]) | ((uint)f2b(acc[i][j][1]) << 16);
          uint hi = (uint)f2b(acc[i][j][2]) | ((uint)f2b(acc[i][j][3]) << 16);
          *(uint2*)&Vo[(size_t)(ng - 2048) * 8192 + mg] = make_uint2(lo, hi);
        }
      }
    }
}

// ---------------------------------------------------------------------------
// Row softmax over 2048 fp32 base-2-domain scores; writes NORMALIZED bf16
// probabilities in-place at the start of the row. One block per row.
// (In-place safe: all row reads happen before the first barrier; writes after
//  the second.)
// ---------------------------------------------------------------------------
__global__ __launch_bounds__(256) void softmax_row(float* __restrict__ S) {
  __shared__ float red[8];
  const int t = threadIdx.x;
  const int w = t >> 6;
  float* row = S + (size_t)blockIdx.x * 2048;

  float4 v0 = *(const float4*)(row + t * 8);
  float4 v1 = *(const float4*)(row + t * 8 + 4);
  float v[8] = {v0.x, v0.y, v0.z, v0.w, v1.x, v1.y, v1.z, v1.w};

  float mx = v[0];
#pragma unroll
  for (int i = 1; i < 8; ++i) mx = fmaxf(mx, v[i]);
#pragma unroll
  for (int d = 1; d < 64; d <<= 1) mx = fmaxf(mx, __shfl_xor(mx, d));
  if ((t & 63) == 0) red[w] = mx;
  __syncthreads();
  mx = fmaxf(fmaxf(red[0], red[1]), fmaxf(red[2], red[3]));

  float p[8], sum = 0.f;
#pragma unroll
  for (int i = 0; i < 8; ++i) { p[i] = exp2f(v[i] - mx); sum += p[i]; }
#pragma unroll
  for (int d = 1; d < 64; d <<= 1) sum += __shfl_xor(sum, d);
  if ((t & 63) == 0) red[4 + w] = sum;
  __syncthreads();
  const float inv = 1.0f / (red[4] + red[5] + red[6] + red[7]);

  short8 o;
#pragma unroll
  for (int i = 0; i < 8; ++i) o[i] = (short)f2b(p[i] * inv);
  *(short8*)((ushort*)row + t * 8) = o;
}

// ---------------------------------------------------------------------------
extern "C" void kernel_launch(void* const* d_in, const int* in_sizes, int n_in,
                              void* d_out, int out_size, void* d_ws, size_t ws_size,
                              hipStream_t stream) {
  const float* x  = (const float*)d_in[0];
  const float* Wq = (const float*)d_in[1];
  const float* Wk = (const float*)d_in[2];
  const float* Wv = (const float*)d_in[3];
  float* outp = (float*)d_out;

  const float SCALE = 1.4426950408889634f / 32.0f;   // log2(e)/sqrt(1024)

  const size_t NEED_1B   = 90177536;    // bf16 block (70 MiB) + 1-batch S
  const size_t NEED_FULL = 140509184;   // bf16 block + full S (64 MiB)

  // ws layout
  ushort* xb = (ushort*)d_ws;                 // [8192][1024]
  ushort* Wb = xb + (size_t)8192 * 1024;      // [3072][1024] (Wq|Wk|Wv)
  ushort* Qb = Wb + (size_t)3 * 1024 * 1024;  // [8192][1024]
  ushort* Kb = Qb + (size_t)8192 * 1024;      // [8192][1024]
  ushort* Vt = Kb + (size_t)8192 * 1024;      // [1024][8192] (d-major)
  float*  S  = (float*)(Vt + (size_t)8192 * 1024);

  cvt_all<<<5632, 256, 0, stream>>>(x, Wq, Wk, Wv, xb, Wb);

  // fused QKV projection: [8192x1024] x [3072x1024]^T
  gemm_bt<4><<<dim3(24, 64, 1), 256, 0, stream>>>(
      xb, 1024, 0, Wb, 1024, 0, Qb, 0, 0, 1024, 1.f);

  if (ws_size >= NEED_FULL) {
    gemm_bt<2><<<dim3(16, 16, 4), 256, 0, stream>>>(
        Qb, 1024, (size_t)2048 * 1024, Kb, 1024, (size_t)2048 * 1024,
        S, 2048, (size_t)2048 * 2048, 1024, SCALE);
    softmax_row<<<8192, 256, 0, stream>>>(S);
    gemm_bt<3><<<dim3(8, 16, 4), 256, 0, stream>>>(
        (const ushort*)S, 4096, (size_t)2048 * 4096, Vt, 8192, 2048,
        outp, 1024, (size_t)2048 * 1024, 2048, 1.f);
  } else {
    // per-batch S buffer (needs NEED_1B)
    for (int b = 0; b < 4; ++b) {
      gemm_bt<2><<<dim3(16, 16, 1), 256, 0, stream>>>(
          Qb + (size_t)b * 2048 * 1024, 1024, 0,
          Kb + (size_t)b * 2048 * 1024, 1024, 0,
          S, 2048, 0, 1024, SCALE);
      softmax_row<<<2048, 256, 0, stream>>>(S);
      gemm_bt<3><<<dim3(8, 16, 1), 256, 0, stream>>>(
          (const ushort*)S, 4096, 0, Vt + (size_t)b * 2048, 8192, 0,
          outp + (size_t)b * 2048 * 1024, 1024, 0, 2048, 1.f);
    }
  }
}